// Round 11
// baseline (231.620 us; speedup 1.0000x reference)
//
#include <hip/hip_runtime.h>

typedef float v4f __attribute__((ext_vector_type(4)));
typedef unsigned int u32;
typedef __attribute__((ext_vector_type(2))) u32 u32x2;
typedef __attribute__((ext_vector_type(4))) u32 u32x4;
typedef __attribute__((ext_vector_type(8))) short bhalf8;
typedef _Float16 half8 __attribute__((ext_vector_type(8)));

#define K 128
#define W_BIJ 1000.0f
#define W_ORTH 1000.0f
#define W_LAP 1.0f
#define W_PRE 100000.0f

#define NCH 79          // ceil(5000/64) V-chunks of 64
#define TILE_B 16384    // one chunk tile: 128 rows x 64 k f16
#define CTILE_B 32768   // 128 x 128 bf16 tile
#define WSLOT_B 12288   // per (mn,d) w slot: 4 quarters x 1536 f16 x 2B
#define WQ_B 3072       // one w quarter: 1536 f16 (1280 used, rest 0)

union B8 { u32x4 u; bhalf8 h; };    // bf16 frags (stage2)
union H8 { u32x4 u; half8 h; };     // f16 frags (stage1)

static __device__ __forceinline__ unsigned short f2b(float x) {
    union { float f; unsigned int u; } v; v.f = x;
    unsigned int u = v.u + 0x7FFFu + ((v.u >> 16) & 1u);   // RNE
    return (unsigned short)(u >> 16);
}
static __device__ __forceinline__ u32 pk2(float lo, float hi) {
    return (u32)f2b(lo) | ((u32)f2b(hi) << 16);
}
static __device__ __forceinline__ u32 pkh(float lo, float hi) {   // 2xf32 -> 2xf16
    u32 r; asm("v_cvt_pkrtz_f16_f32 %0, %1, %2" : "=v"(r) : "v"(lo), "v"(hi)); return r;
}
static __device__ __forceinline__ u32 pkmul(u32 a, u32 b) {       // packed f16 mul
    u32 r; asm("v_pk_mul_f16 %0, %1, %2" : "=v"(r) : "v"(a), "v"(b)); return r;
}
static __device__ __forceinline__ float bitsf(u32 x) {
    union { u32 u; float f; } v; v.u = x; return v.f;
}
static __device__ __forceinline__ void gload_lds16(const void* g, void* l) {
    __builtin_amdgcn_global_load_lds((const __attribute__((address_space(1))) u32*)g,
                                     (__attribute__((address_space(3))) u32*)l, 16, 0, 0);
}

// ============================= conv kernel ==================================
// blocks [0,1264):      Abf tiles  (T1/T2 -> row-major swizzled 128x64 F16)
// blocks [1264,2528):   Ebf tiles  (E1/E2 -> transposed [j][v] F16, row 128B)
// blocks [2528,2928):   Fbf        (feat col gather -> F16 v-pairs, quarter-padded)
// blocks [2928,2944):   Cbf        (C12/C21 -> n-layout + t-layout bf16, stage2)
extern "C" __global__ __launch_bounds__(256, 2)
void surfm_conv(const float* __restrict__ T1, const float* __restrict__ T2,
                const float* __restrict__ E1, const float* __restrict__ E2,
                const float* __restrict__ F1, const float* __restrict__ F2,
                const float* __restrict__ C12g, const float* __restrict__ C21g,
                const int* __restrict__ desc,
                unsigned short* __restrict__ Abf, unsigned short* __restrict__ Ebf,
                char* __restrict__ Fbf, char* __restrict__ Cbf,
                int V, int CF)
{
    __shared__ char csm[36992];
    const int b = blockIdx.x;
    const int tid = threadIdx.x;

    if (b < 1264) {
        // ---- Abf: [mn][c] tiles, (r,k) pre-swizzled, f16 ----
        const int c  = b % NCH;
        const int mn = b / NCH;
        const float* src = ((mn & 8) ? T2 : T1) + (size_t)(mn & 7) * K * V;
        char* dst = (char*)Abf + (size_t)b * TILE_B;
        #pragma unroll
        for (int it = 0; it < 4; ++it) {
            const int item = it * 256 + tid;         // 1024 = 128 r x 8 grp
            const int grp = item & 7, r = item >> 3;
            const int kg = grp ^ (r & 7);
            const int k = c * 64 + kg * 8;
            u32x4 o = (u32x4){0u,0u,0u,0u};
            if (k + 8 <= V) {
                const v4f lo = *(const v4f*)(src + (size_t)r * V + k);
                const v4f hi = *(const v4f*)(src + (size_t)r * V + k + 4);
                o[0] = pkh(lo[0], lo[1]); o[1] = pkh(lo[2], lo[3]);
                o[2] = pkh(hi[0], hi[1]); o[3] = pkh(hi[2], hi[3]);
            }
            *(u32x4*)(dst + r * 128 + grp * 16) = o;
        }
    } else if (b < 2528) {
        // ---- Ebf: transposed [j=128][v=64] f16, v-pairs packed, row 128B ----
        const int idx = b - 1264;
        const int c  = idx % NCH;
        const int mn = idx / NCH;
        const float* src = ((mn & 8) ? E2 : E1) + (size_t)(mn & 7) * V * K;
        char* dst = (char*)Ebf + (size_t)idx * TILE_B;
        #pragma unroll
        for (int it = 0; it < 8; ++it) {
            const int item = it * 256 + tid;          // 2048 = 32 vp x 32 j4
            const int vp = item >> 5;
            const int j4 = (item & 31) * 4;
            const int v = c * 64 + vp * 2;
            v4f e0 = {0.f,0.f,0.f,0.f}, e1 = e0;
            if (v < V)     e0 = *(const v4f*)(src + (size_t)v * K + j4);
            if (v + 1 < V) e1 = *(const v4f*)(src + (size_t)(v + 1) * K + j4);
            #pragma unroll
            for (int e = 0; e < 4; ++e) {
                const int j = j4 + e;
                *(u32*)(csm + j * 128 + vp * 4) = pkh(e0[e], e1[e]);
            }
        }
        __syncthreads();
        #pragma unroll
        for (int it = 0; it < 4; ++it) {
            const int item = it * 256 + tid;
            *(u32x4*)(dst + item * 16) = *(const u32x4*)(csm + item * 16);
        }
    } else if (b < 2928) {
        // ---- Fbf: w f16 v-pairs, 4 quarters x 1536 f16 (1280 used) ----
        const int idx = b - 2528;                     // mn*25 + d
        const int d  = idx % 25;
        const int mn = idx / 25;
        const int col = desc[d];
        const float* src = ((mn & 8) ? F2 : F1) + (size_t)(mn & 7) * V * CF + col;
        u32* dst = (u32*)(Fbf + (size_t)idx * WSLOT_B);
        for (int i = tid; i < 3072; i += 256) {       // 3072 u32 = 4 q x 768
            const int q = i / 768, r = i - q * 768;
            const int v0 = q * 1280 + r * 2;
            u32 val = 0u;
            if (r < 640) {
                const float f0 = (v0 < V)     ? src[(size_t)v0 * CF]       : 0.f;
                const float f1 = (v0 + 1 < V) ? src[(size_t)(v0 + 1) * CF] : 0.f;
                val = pkh(f0, f1);
            }
            dst[i] = val;
        }
    } else {
        // ---- Cbf: n-layout + t-layout 128x128 bf16 tiles (stage2 format) ----
        const int idx = b - 2928;                     // mat*8 + n
        const float* src = ((idx & 8) ? C21g : C12g) + (size_t)(idx & 7) * K * K;
        char* outN = Cbf + (size_t)(idx * 2 + 0) * CTILE_B;
        char* outT = Cbf + (size_t)(idx * 2 + 1) * CTILE_B;
        #pragma unroll
        for (int it = 0; it < 8; ++it) {
            const int item = it * 256 + tid;          // 2048 = 128 r x 16 grp
            const int r = item >> 4, grp = item & 15;
            const int g = grp ^ (r & 7);
            const v4f lo = *(const v4f*)(src + r * K + g * 8);
            const v4f hi = *(const v4f*)(src + r * K + g * 8 + 4);
            u32x4 o;
            o[0] = pk2(lo[0], lo[1]); o[1] = pk2(lo[2], lo[3]);
            o[2] = pk2(hi[0], hi[1]); o[3] = pk2(hi[2], hi[3]);
            *(u32x4*)(outN + r * 256 + grp * 16) = o;
        }
        #pragma unroll
        for (int it = 0; it < 8; ++it) {
            const int item = it * 256 + tid;          // 2048 = 64 rp x 32 j4
            const int rp = item >> 5;
            const int j4 = (item & 31) * 4;
            const v4f r0 = *(const v4f*)(src + (2 * rp) * K + j4);
            const v4f r1 = *(const v4f*)(src + (2 * rp + 1) * K + j4);
            #pragma unroll
            for (int e = 0; e < 4; ++e) {
                const int j = j4 + e;
                *(u32*)(csm + j * 256 + ((rp * 4) ^ ((j & 7) << 4))) = pk2(r0[e], r1[e]);
            }
        }
        __syncthreads();
        #pragma unroll
        for (int it = 0; it < 8; ++it) {
            const int item = it * 256 + tid;
            *(u32x4*)(outT + item * 16) = *(const u32x4*)(csm + item * 16);
        }
    }
}

// ============================= stage 1 ======================================
// R10 f16 datapath + G=3 d-grouping: each A-frag ds_read feeds 3 MFMAs
// (LDS-read pipe no longer binding). 576 blocks x 512 threads:
// b -> n=b&7 (XCD), mat=(b>>3)&1, vq=(b>>4)&3, dgi=b>>6 (9 groups of 3 d).
// 2-phase single-barrier pipeline (R8). LDS = A dbuf 32K + w 9K = 41984 B.
extern "C" __global__ __launch_bounds__(512, 4)
void surfm_stage1(const char* __restrict__ Abf, const char* __restrict__ Ebf,
                  const char* __restrict__ Fbf, char* __restrict__ MpartB)
{
    extern __shared__ char sm[];     // [0,32768) A dbuf; [32768,41984) w f16 x3
    const int tid = threadIdx.x;
    const int l  = tid & 63;
    const int wq = __builtin_amdgcn_readfirstlane(tid >> 6);
    const int b = blockIdx.x;
    const int n = b & 7;
    const int rest = b >> 3;
    const int mat = rest & 1;
    const int vq  = (rest >> 1) & 3;
    const int dgi = rest >> 3;          // 0..8
    const int d0 = dgi * 3;
    const int nD = (25 - d0 < 3) ? (25 - d0) : 3;

    const int mn = mat * 8 + n;
    const char* gA = Abf + (size_t)mn * NCH * TILE_B;
    const char* gE = Ebf + (size_t)mn * NCH * TILE_B;
    const char* gW = Fbf + (size_t)(mn * 25 + d0) * WSLOT_B + vq * WQ_B;
    const int c0 = vq * 20;
    const int NT = (vq == 3) ? 19 : 20;

    const int lm = l & 15;
    const int lk = (l >> 4) * 8;
    const int j  = wq * 16 + lm;            // this wave's private E column
    const int rkey = (lm & 7) << 4;         // A swizzle key
    const char* wB = sm + 32768;

    v4f acc[3][8];
    #pragma unroll
    for (int dd = 0; dd < 3; ++dd)
        #pragma unroll
        for (int mf = 0; mf < 8; ++mf)
            acc[dd][mf] = (v4f){0.f,0.f,0.f,0.f};

    const char* gEl = gE + j * 128 + lk * 2;

    // prologue: w (up to 3 d x 3KB) + A chunk c0 + E chunk c0 regs
    for (int i = wq; i < 9; i += 8) {
        const int dd = i / 3, off = (i - dd * 3) * 1024;
        if (dd < nD)
            gload_lds16(gW + dd * WSLOT_B + off + l * 16,
                        sm + 32768 + dd * WQ_B + off);
    }
    {
        const char* tA = gA + (size_t)c0 * TILE_B;
        gload_lds16(tA + (wq * 2 + 0) * 1024 + l * 16, sm + (wq * 2 + 0) * 1024);
        gload_lds16(tA + (wq * 2 + 1) * 1024 + l * 16, sm + (wq * 2 + 1) * 1024);
    }
    u32x4 eC0 = *(const u32x4*)(gEl + (size_t)c0 * TILE_B);
    u32x4 eC1 = *(const u32x4*)(gEl + (size_t)c0 * TILE_B + 64);
    asm volatile("s_waitcnt vmcnt(0)" ::: "memory");
    __builtin_amdgcn_s_barrier();

    #pragma unroll 1
    for (int t = 0; t < NT; ++t) {
        const int par = t & 1;
        // ---- phase A: issue next-chunk staging BEFORE compute ----
        u32x4 eN0 = eC0, eN1 = eC1;
        if (t + 1 < NT) {
            const char* tA = gA + (size_t)(c0 + t + 1) * TILE_B;
            char* dA = sm + (par ^ 1) * 16384;
            gload_lds16(tA + (wq * 2 + 0) * 1024 + l * 16, dA + (wq * 2 + 0) * 1024);
            gload_lds16(tA + (wq * 2 + 1) * 1024 + l * 16, dA + (wq * 2 + 1) * 1024);
            const char* tE = gEl + (size_t)(c0 + t + 1) * TILE_B;
            eN0 = *(const u32x4*)(tE);
            eN1 = *(const u32x4*)(tE + 64);
        }

        // ---- phase B: compute(t) on buf[par]; pk_mul fold, 3 d per A-frag ----
        const char* Ab = sm + par * 16384;
        #pragma unroll
        for (int ks = 0; ks < 2; ++ks) {
            const u32x4 e = ks ? eC1 : eC0;
            const int wbyte = t * 128 + ks * 64 + lk * 2;
            H8 p[3];
            #pragma unroll
            for (int dd = 0; dd < 3; ++dd) {
                if (dd < nD) {
                    const u32x4 wv = *(const u32x4*)(wB + dd * WQ_B + wbyte);
                    #pragma unroll
                    for (int q = 0; q < 4; ++q) p[dd].u[q] = pkmul(e[q], wv[q]);
                }
            }
            const int kb = ks * 64 + lk * 2;
            __builtin_amdgcn_s_setprio(1);
            #pragma unroll
            for (int mf = 0; mf < 8; ++mf) {
                const int r = mf * 16 + lm;
                H8 a; a.u = *(const u32x4*)(Ab + r * 128 + (kb ^ rkey));
                #pragma unroll
                for (int dd = 0; dd < 3; ++dd)
                    if (dd < nD)
                        acc[dd][mf] = __builtin_amdgcn_mfma_f32_16x16x32_f16(a.h, p[dd].h, acc[dd][mf], 0, 0, 0);
            }
            __builtin_amdgcn_s_setprio(0);
        }
        eC0 = eN0; eC1 = eN1;

        // ---- phase C: drain own staging (had full compute to land), barrier ----
        if (t + 1 < NT) {
            asm volatile("s_waitcnt vmcnt(0)" ::: "memory");
            __builtin_amdgcn_s_barrier();
        }
    }

    // epilogue: bf16 M^T partial stores [col j][row], 8B per mf
    const int slotM = (n * 25 + d0) * 2 + mat;
    const int rbyte = (l >> 4) * 8;
    #pragma unroll
    for (int dd = 0; dd < 3; ++dd) {
        if (dd < nD) {
            char* dst = MpartB + ((size_t)(vq * 400 + slotM + dd * 2)) * 32768 + j * 256 + rbyte;
            #pragma unroll
            for (int mf = 0; mf < 8; ++mf) {
                u32x2 o;
                o[0] = pk2(acc[dd][mf][0], acc[dd][mf][1]);
                o[1] = pk2(acc[dd][mf][2], acc[dd][mf][3]);
                *(u32x2*)(dst + mf * 32) = o;
            }
        }
    }
}

// ============================= mconv ========================================
// 400 blocks: sum 4 bf16 M^T partials (fp32 accum) -> n/t-layout bf16 tiles.
extern "C" __global__ __launch_bounds__(256, 2)
void surfm_mconv(const char* __restrict__ MpartB, char* __restrict__ Mbf)
{
    extern __shared__ char sm[];
    float* sMT = (float*)sm;                  // [128 j][132]
    const int s = blockIdx.x;
    const int tid = threadIdx.x;
    const char* p0 = MpartB + (size_t)s * 32768;
    for (int i = tid; i < 2048; i += 256) {
        const int jj = i >> 4, g = i & 15;
        float sum[8] = {0.f,0.f,0.f,0.f,0.f,0.f,0.f,0.f};
        #pragma unroll
        for (int p = 0; p < 4; ++p) {
            const u32x4 v = *(const u32x4*)(p0 + (size_t)p * 400 * 32768 + jj * 256 + g * 16);
            #pragma unroll
            for (int e = 0; e < 4; ++e) {
                sum[2 * e + 0] += bitsf(v[e] << 16);
                sum[2 * e + 1] += bitsf(v[e] & 0xFFFF0000u);
            }
        }
        float* q = sMT + jj * 132 + g * 8;
        #pragma unroll
        for (int e = 0; e < 8; ++e) q[e] = sum[e];
    }
    __syncthreads();
    char* outN = Mbf + (size_t)s * 65536;
    char* outT = outN + 32768;
    #pragma unroll
    for (int it = 0; it < 16; ++it) {
        const int item = it * 256 + tid;       // 4096 = 2 lay x (128 r x 16 grp)
        const int lay = item >> 11;
        const int g2 = item & 2047;
        const int rr = g2 >> 4, grp = g2 & 15;
        const int g = grp ^ (rr & 7);
        u32x4 o;
        if (lay == 0) {                        // t-layout: M^T row rr contiguous
            const float* p = sMT + rr * 132 + g * 8;
            const v4f a = *(const v4f*)p, bq = *(const v4f*)(p + 4);
            o[0] = pk2(a[0], a[1]);   o[1] = pk2(a[2], a[3]);
            o[2] = pk2(bq[0], bq[1]); o[3] = pk2(bq[2], bq[3]);
            *(u32x4*)(outT + rr * 256 + grp * 16) = o;
        } else {                               // n-layout: M row rr = sMT column
            const float* p = sMT + (g * 8) * 132 + rr;
            o[0] = pk2(p[0],   p[132]); o[1] = pk2(p[264], p[396]);
            o[2] = pk2(p[528], p[660]); o[3] = pk2(p[792], p[924]);
            *(u32x4*)(outN + rr * 256 + grp * 16) = o;
        }
    }
}

// ============================= stage 2 ======================================
// blocks [0,200): l_pre residual GEMMs via MFMA from pre-built bf16 tiles.
// blocks [200,232): small losses (bij/orth/lap), verified fp32 path.
extern "C" __global__ __launch_bounds__(256, 1)
void surfm_stage2(const float* __restrict__ C12g, const float* __restrict__ C21g,
                  const float* __restrict__ ev1g, const float* __restrict__ ev2g,
                  const char* __restrict__ Cbf, const char* __restrict__ Mbf,
                  float* __restrict__ out, int N, int ND)
{
    extern __shared__ char sm[];
    const int b = blockIdx.x;
    const int tid = threadIdx.x;
    const int nPre = N * ND;

    if (b < nPre) {
        const int n = b & 7, d = b >> 3;
        const size_t slot = n * 25 + d;
        const int l = tid & 63;
        const int wq = __builtin_amdgcn_readfirstlane(tid >> 6);
        const int lm = l & 15, lk = (l >> 4) * 8;
        const int wm = wq >> 1, wj = wq & 1;
        float rsum = 0.0f;

        #pragma unroll 1
        for (int ph = 0; ph < 2; ++ph) {
            const char* s0 = Cbf + ((size_t)(ph * 8 + n) * 2 + 0) * CTILE_B;
            const char* s1 = Mbf + (slot * 2 + (ph ? 1 : 0)) * 65536 + 32768;
            const char* s2 = Mbf + (slot * 2 + (ph ? 0 : 1)) * 65536;
            const char* s3 = Cbf + ((size_t)(ph * 8 + n) * 2 + 1) * CTILE_B;
            const char* gs = (wq == 0) ? s0 : (wq == 1) ? s1 : (wq == 2) ? s2 : s3;
            char* ld = sm + wq * 32768;
            if (ph) __builtin_amdgcn_s_barrier();
            #pragma unroll
            for (int i = 0; i < 32; ++i)
                gload_lds16(gs + i * 1024 + l * 16, ld + i * 1024);
            asm volatile("s_waitcnt vmcnt(0)" ::: "memory");
            __builtin_amdgcn_s_barrier();
            __builtin_amdgcn_sched_barrier(0);

            v4f as_[4][4], at_[4][4];
            #pragma unroll
            for (int mf = 0; mf < 4; ++mf)
                #pragma unroll
                for (int jf = 0; jf < 4; ++jf) {
                    as_[mf][jf] = (v4f){0.f,0.f,0.f,0.f};
                    at_[mf][jf] = (v4f){0.f,0.f,0.f,0.f};
                }
            #pragma unroll
            for (int ks = 0; ks < 4; ++ks) {
                const int kb = ks * 64 + lk * 2;
                B8 bS[4], bT[4];
                #pragma unroll
                for (int jf = 0; jf < 4; ++jf) {
                    const int jj = wj * 64 + jf * 16 + lm;
                    const int off = jj * 256 + (kb ^ ((jj & 7) << 4));
                    bS[jf].u = *(const u32x4*)(sm + 32768 + off);
                    bT[jf].u = *(const u32x4*)(sm + 98304 + off);
                }
                #pragma unroll
                for (int mf = 0; mf < 4; ++mf) {
                    const int r = wm * 64 + mf * 16 + lm;
                    const int off = r * 256 + (kb ^ ((r & 7) << 4));
                    B8 aS; aS.u = *(const u32x4*)(sm + off);
                    B8 aT; aT.u = *(const u32x4*)(sm + 65536 + off);
                    #pragma unroll
                    for (int jf = 0; jf < 4; ++jf) {
                        as_[mf][jf] = __builtin_amdgcn_mfma_f32_16x16x32_bf16(aS.h, bS[jf].h, as_[mf][jf], 0, 0, 0);
                        at_[mf][jf] = __builtin_amdgcn_mfma_f32_16x16x32_bf16(aT.h, bT[jf].h, at_[mf][jf], 0, 0, 0);
                    }
                }
            }
            #pragma unroll
            for (int mf = 0; mf < 4; ++mf)
                #pragma unroll
                for (int jf = 0; jf < 4; ++jf) {
                    const v4f df = as_[mf][jf] - at_[mf][jf];
                    rsum += df[0]*df[0] + df[1]*df[1] + df[2]*df[2] + df[3]*df[3];
                }
        }
        #pragma unroll
        for (int off = 32; off; off >>= 1) rsum += __shfl_down(rsum, off, 64);
        if (l == 0)
            atomicAdd(out + 3, rsum * (W_PRE / (float)(N * K * K)));
    } else {
        // --------------------------- small losses ---------------------------
        float* lds = (float*)sm;
        const int idx = b - nPre;
        const int n = idx >> 2, p = idx & 3;
        const float* c12 = C12g + (size_t)n * K * K;
        const float* c21 = C21g + (size_t)n * K * K;
        const float* Xg = (p == 1 || p == 3) ? c21 : c12;
        const float* Yg = (p == 0) ? c21 : c12;
        const float* ea = (p == 0) ? ev1g + n * K : ev2g + n * K;
        const float* eb = (p == 0) ? ev2g + n * K : ev1g + n * K;
        float* X = lds;             // [K][129]
        float* Y = lds + K * 129;
        const int tx = tid & 15, ty = tid >> 4;
        float lap = 0.0f;
        for (int i = tid; i < K * K / 4; i += 256) {
            const int r = i >> 5, c4 = (i & 31) * 4;
            const v4f x = *(const v4f*)(Xg + r * K + c4);
            X[r * 129 + c4 + 0] = x[0]; X[r * 129 + c4 + 1] = x[1];
            X[r * 129 + c4 + 2] = x[2]; X[r * 129 + c4 + 3] = x[3];
            if (p < 2) {
                const v4f y = *(const v4f*)(Yg + r * K + c4);
                Y[r * 129 + c4 + 0] = y[0]; Y[r * 129 + c4 + 1] = y[1];
                Y[r * 129 + c4 + 2] = y[2]; Y[r * 129 + c4 + 3] = y[3];
                const float ebi = eb[r];
                #pragma unroll
                for (int e = 0; e < 4; ++e) {
                    const float dlt = ea[c4 + e] - ebi;
                    lap += x[e] * x[e] * dlt * dlt;
                }
            }
        }
        __syncthreads();
        const int i0 = ty * 8, k0 = tx * 8;
        float z[8][8];
        #pragma unroll
        for (int i = 0; i < 8; ++i)
            #pragma unroll
            for (int t = 0; t < 8; ++t) z[i][t] = 0.0f;
        for (int jj = 0; jj < K; ++jj) {
            float xi[8], yk[8];
            if (p < 2) {
                #pragma unroll
                for (int i = 0; i < 8; ++i) xi[i] = X[(i0 + i) * 129 + jj];
                #pragma unroll
                for (int t = 0; t < 8; ++t) yk[t] = Y[jj * 129 + k0 + t];
            } else {
                #pragma unroll
                for (int i = 0; i < 8; ++i) xi[i] = X[jj * 129 + i0 + i];
                #pragma unroll
                for (int t = 0; t < 8; ++t) yk[t] = X[jj * 129 + k0 + t];
            }
            #pragma unroll
            for (int i = 0; i < 8; ++i)
                #pragma unroll
                for (int t = 0; t < 8; ++t) z[i][t] += xi[i] * yk[t];
        }
        float sacc = 0.0f;
        #pragma unroll
        for (int i = 0; i < 8; ++i)
            #pragma unroll
            for (int t = 0; t < 8; ++t) {
                const float e = z[i][t] - ((i0 + i) == (k0 + t) ? 1.0f : 0.0f);
                sacc += e * e;
            }
        #pragma unroll
        for (int off = 32; off; off >>= 1) {
            sacc += __shfl_down(sacc, off, 64);
            lap  += __shfl_down(lap, off, 64);
        }
        if ((tid & 63) == 0) {
            if (p < 2) {
                atomicAdd(out + 0, sacc * (W_BIJ / (float)N));
                atomicAdd(out + 2, lap * (W_LAP / (float)N));
            } else {
                atomicAdd(out + 1, sacc * (W_ORTH / (float)N));
            }
        }
    }
}

// ================= fallback: round-2 verified fused kernel =================
extern "C" __global__ __launch_bounds__(256, 1)
void surfm_fused(const float* __restrict__ C12g, const float* __restrict__ C21g,
                 const float* __restrict__ F1, const float* __restrict__ F2,
                 const float* __restrict__ E1g, const float* __restrict__ E2g,
                 const float* __restrict__ T1, const float* __restrict__ T2,
                 const float* __restrict__ ev1g, const float* __restrict__ ev2g,
                 const int* __restrict__ desc, float* __restrict__ out,
                 int N, int ND, int V, int CF)
{
    extern __shared__ char smem[];
    const int b   = blockIdx.x;
    const int tid = threadIdx.x;
    const int nPre = N * ND;

    if (b < nPre) {
        const int n = b & 7;
        const int d = b >> 3;
        const int col = desc[d];
        const float* A1g = T1 + (size_t)n * K * V;
        const float* A2g = T2 + (size_t)n * K * V;
        const float* B1g = E1g + (size_t)n * V * K;
        const float* B2g = E2g + (size_t)n * V * K;
        const float* w1g = F1 + (size_t)n * V * CF;
        const float* w2g = F2 + (size_t)n * V * CF;

        char* As1 = smem;
        char* As2 = smem + 32768;
        char* Bt1 = smem + 65536;
        char* Bt2 = smem + 98304;

        const int l  = tid & 63;
        const int w  = tid >> 6;
        const int lm = l & 15;
        const int lk = (l >> 4) * 8;

        v4f acc1[8][2], acc2[8][2];
        #pragma unroll
        for (int mf = 0; mf < 8; ++mf)
            #pragma unroll
            for (int jf = 0; jf < 2; ++jf) {
                acc1[mf][jf] = (v4f){0.f,0.f,0.f,0.f};
                acc2[mf][jf] = (v4f){0.f,0.f,0.f,0.f};
            }

        for (int v0 = 0; v0 < V; v0 += 128) {
            __syncthreads();
            #pragma unroll 4
            for (int it = 0; it < 16; ++it) {
                const int i  = it * 256 + tid;
                const int r  = i >> 5;
                const int c4 = (i & 31) * 4;
                const int vg = v0 + c4;
                v4f a1 = {0.f,0.f,0.f,0.f}, a2 = {0.f,0.f,0.f,0.f};
                if (vg < V) {
                    a1 = *(const v4f*)(A1g + (size_t)r * V + vg);
                    a2 = *(const v4f*)(A2g + (size_t)r * V + vg);
                }
                const int byte = (r * 256 + c4 * 2) ^ ((r & 7) << 4);
                short4 p1, p2;
                p1.x = (short)f2b(a1[0]); p1.y = (short)f2b(a1[1]);
                p1.z = (short)f2b(a1[2]); p1.w = (short)f2b(a1[3]);
                p2.x = (short)f2b(a2[0]); p2.y = (short)f2b(a2[1]);
                p2.z = (short)f2b(a2[2]); p2.w = (short)f2b(a2[3]);
                *(short4*)(As1 + byte) = p1;
                *(short4*)(As2 + byte) = p2;
            }
            #pragma unroll 2
            for (int it = 0; it < 8; ++it) {
                const int i  = it * 256 + tid;
                const int j4 = (i & 31) * 4;
                const int vp = (i >> 5) * 2;
                const int va = v0 + vp, vb = va + 1;
                v4f e1a = {0.f,0.f,0.f,0.f}, e1b = e1a, e2a = e1a, e2b = e1a;
                if (va < V) {
                    const float w1 = w1g[(size_t)va * CF + col];
                    const float w2 = w2g[(size_t)va * CF + col];
                    e1a = *(const v4f*)(B1g + (size_t)va * K + j4) * w1;
                    e2a = *(const v4f*)(B2g + (size_t)va * K + j4) * w2;
                }
                if (vb < V) {
                    const float w1 = w1g[(size_t)vb * CF + col];
                    const float w2 = w2g[(size_t)vb * CF + col];
                    e1b = *(const v4f*)(B1g + (size_t)vb * K + j4) * w1;
                    e2b = *(const v4f*)(B2g + (size_t)vb * K + j4) * w2;
                }
                #pragma unroll
                for (int e = 0; e < 4; ++e) {
                    const int j = j4 + e;
                    const int key = (((j & 7) ^ ((j >> 3) & 7)) << 4);
                    const int byte = (j * 256 + vp * 2) ^ key;
                    *(u32*)(Bt1 + byte) = pk2(e1a[e], e1b[e]);
                    *(u32*)(Bt2 + byte) = pk2(e2a[e], e2b[e]);
                }
            }
            __syncthreads();
            #pragma unroll
            for (int ks = 0; ks < 4; ++ks) {
                const int k0 = ks * 32 + lk;
                bhalf8 bB1[2], bB2[2];
                #pragma unroll
                for (int jf = 0; jf < 2; ++jf) {
                    const int j = w * 32 + jf * 16 + lm;
                    const int key = (((j & 7) ^ ((j >> 3) & 7)) << 4);
                    const int byte = (j * 256 + k0 * 2) ^ key;
                    bB1[jf] = *(const bhalf8*)(Bt1 + byte);
                    bB2[jf] = *(const bhalf8*)(Bt2 + byte);
                }
                #pragma unroll
                for (int mf = 0; mf < 8; ++mf) {
                    const int r = mf * 16 + lm;
                    const int byte = (r * 256 + k0 * 2) ^ ((r & 7) << 4);
                    const bhalf8 a1 = *(const bhalf8*)(As1 + byte);
                    const bhalf8 a2 = *(const bhalf8*)(As2 + byte);
                    acc1[mf][0] = __builtin_amdgcn_mfma_f32_16x16x32_bf16(a1, bB1[0], acc1[mf][0], 0, 0, 0);
                    acc1[mf][1] = __builtin_amdgcn_mfma_f32_16x16x32_bf16(a1, bB1[1], acc1[mf][1], 0, 0, 0);
                    acc2[mf][0] = __builtin_amdgcn_mfma_f32_16x16x32_bf16(a2, bB2[0], acc2[mf][0], 0, 0, 0);
                    acc2[mf][1] = __builtin_amdgcn_mfma_f32_16x16x32_bf16(a2, bB2[1], acc2[mf][1], 0, 0, 0);
                }
            }
        }
        __syncthreads();
        float* M1 = (float*)smem;
        float* M2 = (float*)smem + K * K;
        #pragma unroll
        for (int mf = 0; mf < 8; ++mf)
            #pragma unroll
            for (int jf = 0; jf < 2; ++jf)
                #pragma unroll
                for (int rg = 0; rg < 4; ++rg) {
                    const int row = mf * 16 + ((l >> 4) << 2) + rg;
                    const int cj  = w * 32 + jf * 16 + lm;
                    const int pc  = ((((cj >> 2) ^ ((row >> 3) & 7)) << 2) | (cj & 3));
                    M1[row * K + pc] = acc1[mf][jf][rg];
                    M2[row * K + pc] = acc2[mf][jf][rg];
                }
        __syncthreads();

        const int tx = tid & 15, ty = tid >> 4;
        const int r0 = ty * 8;
        const int ca = tx * 4, cb = 64 + tx * 4;
        const int kcol = ty & 7;
        const float* c12 = C12g + (size_t)n * K * K;
        const float* c21 = C21g + (size_t)n * K * K;
        v4f acc1a[8], acc1b[8], acc2a[8], acc2b[8];
        #pragma unroll
        for (int i = 0; i < 8; ++i) {
            acc1a[i] = (v4f){0,0,0,0}; acc1b[i] = (v4f){0,0,0,0};
            acc2a[i] = (v4f){0,0,0,0}; acc2b[i] = (v4f){0,0,0,0};
        }
        for (int jj = 0; jj < K; ++jj) {
            const int keyj = (jj >> 3) & 7;
            const int ga = (tx ^ keyj) << 2;
            const int gb = ((16 + tx) ^ keyj) << 2;
            const v4f m1ra = *(const v4f*)(M1 + jj * K + ga);
            const v4f m1rb = *(const v4f*)(M1 + jj * K + gb);
            const v4f m2ra = *(const v4f*)(M2 + jj * K + ga);
            const v4f m2rb = *(const v4f*)(M2 + jj * K + gb);
            const v4f c12ra = *(const v4f*)(c12 + jj * K + ca);
            const v4f c12rb = *(const v4f*)(c12 + jj * K + cb);
            const v4f c21ra = *(const v4f*)(c21 + jj * K + ca);
            const v4f c21rb = *(const v4f*)(c21 + jj * K + cb);
            const int jp = (((jj >> 2) ^ kcol) << 2) | (jj & 3);
            #pragma unroll
            for (int i = 0; i < 8; ++i) {
                const int r = r0 + i;
                const float x12 = c12[r * K + jj];
                const float x21 = c21[r * K + jj];
                const float m1c = M1[r * K + jp];
                const float m2c = M2[r * K + jp];
                acc1a[i] += m1ra * x12; acc1a[i] -= c12ra * m2c;
                acc1b[i] += m1rb * x12; acc1b[i] -= c12rb * m2c;
                acc2a[i] += m2ra * x21; acc2a[i] -= c21ra * m1c;
                acc2b[i] += m2rb * x21; acc2b[i] -= c21rb * m1c;
            }
        }
        float s = 0.0f;
        #pragma unroll
        for (int i = 0; i < 8; ++i)
            #pragma unroll
            for (int e = 0; e < 4; ++e) {
                s += acc1a[i][e] * acc1a[i][e] + acc1b[i][e] * acc1b[i][e];
                s += acc2a[i][e] * acc2a[i][e] + acc2b[i][e] * acc2b[i][e];
            }
        #pragma unroll
        for (int off = 32; off; off >>= 1) s += __shfl_down(s, off, 64);
        if ((tid & 63) == 0)
            atomicAdd(out + 3, s * (W_PRE / (float)(N * K * K)));
    } else {
        float* ldsf = (float*)smem;
        const int idx = b - nPre;
        const int n = idx >> 2, p = idx & 3;
        const float* c12 = C12g + (size_t)n * K * K;
        const float* c21 = C21g + (size_t)n * K * K;
        const float* Xg = (p == 1 || p == 3) ? c21 : c12;
        const float* Yg = (p == 0) ? c21 : c12;
        const float* ea = (p == 0) ? ev1g + n * K : ev2g + n * K;
        const float* eb = (p == 0) ? ev2g + n * K : ev1g + n * K;
        float* X = ldsf;
        float* Y = ldsf + K * 129;
        const int tx = tid & 15, ty = tid >> 4;
        float lap = 0.0f;
        for (int i = tid; i < K * K / 4; i += 256) {
            const int r = i >> 5, c4 = (i & 31) * 4;
            const v4f x = *(const v4f*)(Xg + r * K + c4);
            X[r * 129 + c4 + 0] = x[0]; X[r * 129 + c4 + 1] = x[1];
            X[r * 129 + c4 + 2] = x[2]; X[r * 129 + c4 + 3] = x[3];
            if (p < 2) {
                const v4f y = *(const v4f*)(Yg + r * K + c4);
                Y[r * 129 + c4 + 0] = y[0]; Y[r * 129 + c4 + 1] = y[1];
                Y[r * 129 + c4 + 2] = y[2]; Y[r * 129 + c4 + 3] = y[3];
                const float ebi = eb[r];
                #pragma unroll
                for (int e = 0; e < 4; ++e) {
                    const float dlt = ea[c4 + e] - ebi;
                    lap += x[e] * x[e] * dlt * dlt;
                }
            }
        }
        __syncthreads();
        const int i0 = ty * 8, k0 = tx * 8;
        float z[8][8];
        #pragma unroll
        for (int i = 0; i < 8; ++i)
            #pragma unroll
            for (int t = 0; t < 8; ++t) z[i][t] = 0.0f;
        for (int jj = 0; jj < K; ++jj) {
            float xi[8], yk[8];
            if (p < 2) {
                #pragma unroll
                for (int i = 0; i < 8; ++i) xi[i] = X[(i0 + i) * 129 + jj];
                #pragma unroll
                for (int t = 0; t < 8; ++t) yk[t] = Y[jj * 129 + k0 + t];
            } else {
                #pragma unroll
                for (int i = 0; i < 8; ++i) xi[i] = X[jj * 129 + i0 + i];
                #pragma unroll
                for (int t = 0; t < 8; ++t) yk[t] = X[jj * 129 + k0 + t];
            }
            #pragma unroll
            for (int i = 0; i < 8; ++i)
                #pragma unroll
                for (int t = 0; t < 8; ++t) z[i][t] += xi[i] * yk[t];
        }
        float s = 0.0f;
        #pragma unroll
        for (int i = 0; i < 8; ++i)
            #pragma unroll
            for (int t = 0; t < 8; ++t) {
                const float e = z[i][t] - ((i0 + i) == (k0 + t) ? 1.0f : 0.0f);
                s += e * e;
            }
        #pragma unroll
        for (int off = 32; off; off >>= 1) {
            s   += __shfl_down(s, off, 64);
            lap += __shfl_down(lap, off, 64);
        }
        if ((tid & 63) == 0) {
            if (p < 2) {
                atomicAdd(out + 0, s * (W_BIJ / (float)N));
                atomicAdd(out + 2, lap * (W_LAP / (float)N));
            } else {
                atomicAdd(out + 1, s * (W_ORTH / (float)N));
            }
        }
    }
}

extern "C" void kernel_launch(void* const* d_in, const int* in_sizes, int n_in,
                              void* d_out, int out_size, void* d_ws, size_t ws_size,
                              hipStream_t stream) {
    (void)n_in;
    const float* C12 = (const float*)d_in[0];
    const float* C21 = (const float*)d_in[1];
    const float* F1  = (const float*)d_in[2];
    const float* F2  = (const float*)d_in[3];
    const float* E1  = (const float*)d_in[4];
    const float* E2  = (const float*)d_in[5];
    const float* T1  = (const float*)d_in[6];
    const float* T2  = (const float*)d_in[7];
    const float* ev1 = (const float*)d_in[8];
    const float* ev2 = (const float*)d_in[9];
    const int* desc  = (const int*)d_in[10];
    float* out = (float*)d_out;

    const int N  = in_sizes[8] / K;            // evals_1: N*K
    const int ND = in_sizes[10];               // desc_ind
    const int V  = in_sizes[4] / (N * K);      // evecs_1: N*V*K
    const int CF = in_sizes[2] / (N * V);      // feat_1: N*V*C

    hipMemsetAsync(d_out, 0, (size_t)out_size * sizeof(float), stream);

    const size_t ABF = (size_t)16 * NCH * TILE_B;        // 20,709,376
    const size_t EBF = ABF;                              // 20,709,376
    const size_t FBF = (size_t)400 * WSLOT_B;            //  4,915,200
    const size_t CBF = (size_t)32 * CTILE_B;             //  1,048,576
    const size_t MBF = (size_t)400 * 65536;              // 26,214,400
    const size_t MPB = (size_t)4 * 400 * 32768;          // 52,428,800
    const size_t base = ABF + EBF + FBF + CBF + MBF;
    const size_t needPart = base + MPB;                  // 126,025,728

    const bool okShape = (N == 8 && ND == 25 && V == 5000 && CF == 128);
    if (!okShape || ws_size < needPart) {
        const size_t shmem = (size_t)(2 * K * 129) * sizeof(float);  // 132096
        hipFuncSetAttribute((const void*)surfm_fused,
                            hipFuncAttributeMaxDynamicSharedMemorySize, (int)shmem);
        const int blocks = N * ND + 4 * N;
        surfm_fused<<<blocks, 256, shmem, stream>>>(C12, C21, F1, F2, E1, E2, T1, T2,
                                                    ev1, ev2, desc, out, N, ND, V, CF);
        return;
    }

    char* ws = (char*)d_ws;
    unsigned short* Abf = (unsigned short*)ws;
    unsigned short* Ebf = (unsigned short*)(ws + ABF);
    char* Fbf = ws + ABF + EBF;
    char* Cbf = ws + ABF + EBF + FBF;
    char* Mbf = ws + ABF + EBF + FBF + CBF;
    char* MpartB = ws + base;

    surfm_conv<<<2944, 256, 0, stream>>>(T1, T2, E1, E2, F1, F2, C12, C21, desc,
                                         Abf, Ebf, Fbf, Cbf, V, CF);

    const size_t shmem1 = 41984;    // A dbuf 32K + w 9K (G=3)
    hipFuncSetAttribute((const void*)surfm_stage1,
                        hipFuncAttributeMaxDynamicSharedMemorySize, (int)shmem1);
    surfm_stage1<<<576, 512, shmem1, stream>>>((const char*)Abf, (const char*)Ebf,
                                               Fbf, MpartB);

    const size_t shmemM = (size_t)128 * 132 * 4;   // 67584
    hipFuncSetAttribute((const void*)surfm_mconv,
                        hipFuncAttributeMaxDynamicSharedMemorySize, (int)shmemM);
    surfm_mconv<<<400, 256, shmemM, stream>>>(MpartB, Mbf);

    const size_t shmem2 = 132096;
    hipFuncSetAttribute((const void*)surfm_stage2,
                        hipFuncAttributeMaxDynamicSharedMemorySize, (int)shmem2);
    surfm_stage2<<<N * ND + 4 * N, 256, shmem2, stream>>>(C12, C21, ev1, ev2,
                                                          Cbf, Mbf, out, N, ND);
}

// Round 12
// 180.670 us; speedup vs baseline: 1.2820x; 1.2820x over previous
//
#include <hip/hip_runtime.h>

typedef float v4f __attribute__((ext_vector_type(4)));
typedef unsigned int u32;
typedef __attribute__((ext_vector_type(2))) u32 u32x2;
typedef __attribute__((ext_vector_type(4))) u32 u32x4;
typedef __attribute__((ext_vector_type(8))) short bhalf8;
typedef _Float16 half8 __attribute__((ext_vector_type(8)));

#define K 128
#define W_BIJ 1000.0f
#define W_ORTH 1000.0f
#define W_LAP 1.0f
#define W_PRE 100000.0f

#define NCH 79          // ceil(5000/64) V-chunks of 64
#define TILE_B 16384    // one chunk tile: 128 rows x 64 k f16
#define CTILE_B 32768   // 128 x 128 bf16 tile
#define WSLOT_B 10240   // per (mn,d) w slot: 2 halves x 1280 u32 (2560 f16)
#define WH_B 5120       // one w half: 40 chunks x 128 B

union B8 { u32x4 u; bhalf8 h; };    // bf16 frags (stage2)
union H8 { u32x4 u; half8 h; };     // f16 frags (stage1)

static __device__ __forceinline__ unsigned short f2b(float x) {
    union { float f; unsigned int u; } v; v.f = x;
    unsigned int u = v.u + 0x7FFFu + ((v.u >> 16) & 1u);   // RNE
    return (unsigned short)(u >> 16);
}
static __device__ __forceinline__ u32 pk2(float lo, float hi) {
    return (u32)f2b(lo) | ((u32)f2b(hi) << 16);
}
static __device__ __forceinline__ u32 pkh(float lo, float hi) {   // 2xf32 -> 2xf16
    u32 r; asm("v_cvt_pkrtz_f16_f32 %0, %1, %2" : "=v"(r) : "v"(lo), "v"(hi)); return r;
}
static __device__ __forceinline__ u32 pkmul(u32 a, u32 b) {       // packed f16 mul
    u32 r; asm("v_pk_mul_f16 %0, %1, %2" : "=v"(r) : "v"(a), "v"(b)); return r;
}
static __device__ __forceinline__ float bitsf(u32 x) {
    union { u32 u; float f; } v; v.u = x; return v.f;
}
static __device__ __forceinline__ void gload_lds16(const void* g, void* l) {
    __builtin_amdgcn_global_load_lds((const __attribute__((address_space(1))) u32*)g,
                                     (__attribute__((address_space(3))) u32*)l, 16, 0, 0);
}

// ============================= conv kernel ==================================
// blocks [0,1264):      Abf tiles  (T1/T2 -> row-major swizzled 128x64 F16)
// blocks [1264,2528):   Ebf tiles  (E1/E2 -> transposed [j][v] F16, row 128B)
// blocks [2528,2928):   Fbf        (feat col gather -> F16 v-pairs, 2 halves)
// blocks [2928,2944):   Cbf        (C12/C21 -> n-layout + t-layout bf16, stage2)
extern "C" __global__ __launch_bounds__(256, 2)
void surfm_conv(const float* __restrict__ T1, const float* __restrict__ T2,
                const float* __restrict__ E1, const float* __restrict__ E2,
                const float* __restrict__ F1, const float* __restrict__ F2,
                const float* __restrict__ C12g, const float* __restrict__ C21g,
                const int* __restrict__ desc,
                unsigned short* __restrict__ Abf, unsigned short* __restrict__ Ebf,
                char* __restrict__ Fbf, char* __restrict__ Cbf,
                int V, int CF)
{
    __shared__ char csm[36992];
    const int b = blockIdx.x;
    const int tid = threadIdx.x;

    if (b < 1264) {
        // ---- Abf: [mn][c] tiles, (r,k) pre-swizzled, f16 ----
        const int c  = b % NCH;
        const int mn = b / NCH;
        const float* src = ((mn & 8) ? T2 : T1) + (size_t)(mn & 7) * K * V;
        char* dst = (char*)Abf + (size_t)b * TILE_B;
        #pragma unroll
        for (int it = 0; it < 4; ++it) {
            const int item = it * 256 + tid;         // 1024 = 128 r x 8 grp
            const int grp = item & 7, r = item >> 3;
            const int kg = grp ^ (r & 7);
            const int k = c * 64 + kg * 8;
            u32x4 o = (u32x4){0u,0u,0u,0u};
            if (k + 8 <= V) {
                const v4f lo = *(const v4f*)(src + (size_t)r * V + k);
                const v4f hi = *(const v4f*)(src + (size_t)r * V + k + 4);
                o[0] = pkh(lo[0], lo[1]); o[1] = pkh(lo[2], lo[3]);
                o[2] = pkh(hi[0], hi[1]); o[3] = pkh(hi[2], hi[3]);
            }
            *(u32x4*)(dst + r * 128 + grp * 16) = o;
        }
    } else if (b < 2528) {
        // ---- Ebf: transposed [j=128][v=64] f16, v-pairs packed, row 128B ----
        const int idx = b - 1264;
        const int c  = idx % NCH;
        const int mn = idx / NCH;
        const float* src = ((mn & 8) ? E2 : E1) + (size_t)(mn & 7) * V * K;
        char* dst = (char*)Ebf + (size_t)idx * TILE_B;
        #pragma unroll
        for (int it = 0; it < 8; ++it) {
            const int item = it * 256 + tid;          // 2048 = 32 vp x 32 j4
            const int vp = item >> 5;
            const int j4 = (item & 31) * 4;
            const int v = c * 64 + vp * 2;
            v4f e0 = {0.f,0.f,0.f,0.f}, e1 = e0;
            if (v < V)     e0 = *(const v4f*)(src + (size_t)v * K + j4);
            if (v + 1 < V) e1 = *(const v4f*)(src + (size_t)(v + 1) * K + j4);
            #pragma unroll
            for (int e = 0; e < 4; ++e) {
                const int j = j4 + e;
                *(u32*)(csm + j * 128 + vp * 4) = pkh(e0[e], e1[e]);
            }
        }
        __syncthreads();
        #pragma unroll
        for (int it = 0; it < 4; ++it) {
            const int item = it * 256 + tid;
            *(u32x4*)(dst + item * 16) = *(const u32x4*)(csm + item * 16);
        }
    } else if (b < 2928) {
        // ---- Fbf: w f16 v-pairs, 2 halves x 1280 u32 (no pad needed) ----
        const int idx = b - 2528;                     // mn*25 + d
        const int d  = idx % 25;
        const int mn = idx / 25;
        const int col = desc[d];
        const float* src = ((mn & 8) ? F2 : F1) + (size_t)(mn & 7) * V * CF + col;
        u32* dst = (u32*)(Fbf + (size_t)idx * WSLOT_B);
        for (int i = tid; i < 2560; i += 256) {       // 2560 u32 = 2 h x 1280
            const int h = i >> 11, r = i & 2047;      // h = i/2048? no: 1280/half
            const int hh = i / 1280, rr = i - hh * 1280;
            (void)h; (void)r;
            const int v0 = hh * 2560 + rr * 2;
            u32 val = 0u;
            const float f0 = (v0 < V)     ? src[(size_t)v0 * CF]       : 0.f;
            const float f1 = (v0 + 1 < V) ? src[(size_t)(v0 + 1) * CF] : 0.f;
            if (v0 < V) val = pkh(f0, f1);
            dst[i] = val;
        }
    } else {
        // ---- Cbf: n-layout + t-layout 128x128 bf16 tiles (stage2 format) ----
        const int idx = b - 2928;                     // mat*8 + n
        const float* src = ((idx & 8) ? C21g : C12g) + (size_t)(idx & 7) * K * K;
        char* outN = Cbf + (size_t)(idx * 2 + 0) * CTILE_B;
        char* outT = Cbf + (size_t)(idx * 2 + 1) * CTILE_B;
        #pragma unroll
        for (int it = 0; it < 8; ++it) {
            const int item = it * 256 + tid;          // 2048 = 128 r x 16 grp
            const int r = item >> 4, grp = item & 15;
            const int g = grp ^ (r & 7);
            const v4f lo = *(const v4f*)(src + r * K + g * 8);
            const v4f hi = *(const v4f*)(src + r * K + g * 8 + 4);
            u32x4 o;
            o[0] = pk2(lo[0], lo[1]); o[1] = pk2(lo[2], lo[3]);
            o[2] = pk2(hi[0], hi[1]); o[3] = pk2(hi[2], hi[3]);
            *(u32x4*)(outN + r * 256 + grp * 16) = o;
        }
        #pragma unroll
        for (int it = 0; it < 8; ++it) {
            const int item = it * 256 + tid;          // 2048 = 64 rp x 32 j4
            const int rp = item >> 5;
            const int j4 = (item & 31) * 4;
            const v4f r0 = *(const v4f*)(src + (2 * rp) * K + j4);
            const v4f r1 = *(const v4f*)(src + (2 * rp + 1) * K + j4);
            #pragma unroll
            for (int e = 0; e < 4; ++e) {
                const int j = j4 + e;
                *(u32*)(csm + j * 256 + ((rp * 4) ^ ((j & 7) << 4))) = pk2(r0[e], r1[e]);
            }
        }
        __syncthreads();
        #pragma unroll
        for (int it = 0; it < 8; ++it) {
            const int item = it * 256 + tid;
            *(u32x4*)(outT + item * 16) = *(const u32x4*)(csm + item * 16);
        }
    }
}

// ============================= stage 1 ======================================
// R10-verified f16 structure, vh=2 V-halves (was vq=4): 416 blocks x 512 thr.
// b -> n=b&7 (XCD), mat=(b>>3)&1, vh=(b>>4)&1, dgi=b>>5 (13 groups of 2 d).
// 2-phase single-barrier pipeline. LDS = A dbuf 32K + w 10K = 43008 B.
extern "C" __global__ __launch_bounds__(512, 4)
void surfm_stage1(const char* __restrict__ Abf, const char* __restrict__ Ebf,
                  const char* __restrict__ Fbf, char* __restrict__ MpartB)
{
    extern __shared__ char sm[];     // [0,32768) A dbuf; [32768,43008) w f16
    const int tid = threadIdx.x;
    const int l  = tid & 63;
    const int wq = __builtin_amdgcn_readfirstlane(tid >> 6);
    const int b = blockIdx.x;
    const int n = b & 7;
    const int rest = b >> 3;
    const int mat = rest & 1;
    const int vh  = (rest >> 1) & 1;
    const int dgi = rest >> 2;          // 0..12
    const int d0 = dgi * 2;
    const bool hasD1 = (d0 + 1) < 25;

    const int mn = mat * 8 + n;
    const char* gA = Abf + (size_t)mn * NCH * TILE_B;
    const char* gE = Ebf + (size_t)mn * NCH * TILE_B;
    const char* gW = Fbf + (size_t)(mn * 25 + d0) * WSLOT_B + vh * WH_B;
    const int c0 = vh * 40;
    const int NT = vh ? 39 : 40;

    const int lm = l & 15;
    const int lk = (l >> 4) * 8;
    const int j  = wq * 16 + lm;            // this wave's private E column
    const int rkey = (lm & 7) << 4;         // A swizzle key
    const char* wB = sm + 32768;

    v4f acc0[8], acc1[8];
    #pragma unroll
    for (int mf = 0; mf < 8; ++mf) {
        acc0[mf] = (v4f){0.f,0.f,0.f,0.f};
        acc1[mf] = (v4f){0.f,0.f,0.f,0.f};
    }

    const char* gEl = gE + j * 128 + lk * 2;

    // prologue: w (2 d x 5KB) + A chunk c0 + E chunk c0 regs
    for (int i = wq; i < 10; i += 8) {
        const int dd = i / 5, off = (i - dd * 5) * 1024;
        gload_lds16(gW + dd * WSLOT_B + off + l * 16,
                    sm + 32768 + dd * WH_B + off);
    }
    {
        const char* tA = gA + (size_t)c0 * TILE_B;
        gload_lds16(tA + (wq * 2 + 0) * 1024 + l * 16, sm + (wq * 2 + 0) * 1024);
        gload_lds16(tA + (wq * 2 + 1) * 1024 + l * 16, sm + (wq * 2 + 1) * 1024);
    }
    u32x4 eC0 = *(const u32x4*)(gEl + (size_t)c0 * TILE_B);
    u32x4 eC1 = *(const u32x4*)(gEl + (size_t)c0 * TILE_B + 64);
    asm volatile("s_waitcnt vmcnt(0)" ::: "memory");
    __builtin_amdgcn_s_barrier();

    #pragma unroll 1
    for (int t = 0; t < NT; ++t) {
        const int par = t & 1;
        // ---- phase A: issue next-chunk staging BEFORE compute ----
        u32x4 eN0 = eC0, eN1 = eC1;
        if (t + 1 < NT) {
            const char* tA = gA + (size_t)(c0 + t + 1) * TILE_B;
            char* dA = sm + (par ^ 1) * 16384;
            gload_lds16(tA + (wq * 2 + 0) * 1024 + l * 16, dA + (wq * 2 + 0) * 1024);
            gload_lds16(tA + (wq * 2 + 1) * 1024 + l * 16, dA + (wq * 2 + 1) * 1024);
            const char* tE = gEl + (size_t)(c0 + t + 1) * TILE_B;
            eN0 = *(const u32x4*)(tE);
            eN1 = *(const u32x4*)(tE + 64);
        }

        // ---- phase B: compute(t) on buf[par]; f16 pk_mul fold ----
        const char* Ab = sm + par * 16384;
        #pragma unroll
        for (int ks = 0; ks < 2; ++ks) {
            const u32x4 e = ks ? eC1 : eC0;
            const int wbyte = t * 128 + ks * 64 + lk * 2;
            const u32x4 w0 = *(const u32x4*)(wB + wbyte);
            H8 p0, p1;
            #pragma unroll
            for (int q = 0; q < 4; ++q) p0.u[q] = pkmul(e[q], w0[q]);
            if (hasD1) {
                const u32x4 w1 = *(const u32x4*)(wB + WH_B + wbyte);
                #pragma unroll
                for (int q = 0; q < 4; ++q) p1.u[q] = pkmul(e[q], w1[q]);
            }
            const int kb = ks * 64 + lk * 2;
            __builtin_amdgcn_s_setprio(1);
            #pragma unroll
            for (int mf = 0; mf < 8; ++mf) {
                const int r = mf * 16 + lm;
                H8 a; a.u = *(const u32x4*)(Ab + r * 128 + (kb ^ rkey));
                acc0[mf] = __builtin_amdgcn_mfma_f32_16x16x32_f16(a.h, p0.h, acc0[mf], 0, 0, 0);
                if (hasD1)
                    acc1[mf] = __builtin_amdgcn_mfma_f32_16x16x32_f16(a.h, p1.h, acc1[mf], 0, 0, 0);
            }
            __builtin_amdgcn_s_setprio(0);
        }
        eC0 = eN0; eC1 = eN1;

        // ---- phase C: drain own staging (had full compute to land), barrier ----
        if (t + 1 < NT) {
            asm volatile("s_waitcnt vmcnt(0)" ::: "memory");
            __builtin_amdgcn_s_barrier();
        }
    }

    // epilogue: bf16 M^T partial stores [col j][row], 8B per mf
    const int slotM = (n * 25 + d0) * 2 + mat;
    const int rbyte = (l >> 4) * 8;
    {
        char* dst = MpartB + ((size_t)(vh * 400 + slotM)) * 32768 + j * 256 + rbyte;
        #pragma unroll
        for (int mf = 0; mf < 8; ++mf) {
            u32x2 o;
            o[0] = pk2(acc0[mf][0], acc0[mf][1]);
            o[1] = pk2(acc0[mf][2], acc0[mf][3]);
            *(u32x2*)(dst + mf * 32) = o;
        }
    }
    if (hasD1) {
        char* dst = MpartB + ((size_t)(vh * 400 + slotM + 2)) * 32768 + j * 256 + rbyte;
        #pragma unroll
        for (int mf = 0; mf < 8; ++mf) {
            u32x2 o;
            o[0] = pk2(acc1[mf][0], acc1[mf][1]);
            o[1] = pk2(acc1[mf][2], acc1[mf][3]);
            *(u32x2*)(dst + mf * 32) = o;
        }
    }
}

// ============================= mconv ========================================
// 400 blocks: sum 2 bf16 M^T partials (fp32 accum) -> n/t-layout bf16 tiles.
extern "C" __global__ __launch_bounds__(256, 2)
void surfm_mconv(const char* __restrict__ MpartB, char* __restrict__ Mbf)
{
    extern __shared__ char sm[];
    float* sMT = (float*)sm;                  // [128 j][132]
    const int s = blockIdx.x;
    const int tid = threadIdx.x;
    const char* p0 = MpartB + (size_t)s * 32768;
    for (int i = tid; i < 2048; i += 256) {
        const int jj = i >> 4, g = i & 15;
        float sum[8] = {0.f,0.f,0.f,0.f,0.f,0.f,0.f,0.f};
        #pragma unroll
        for (int p = 0; p < 2; ++p) {
            const u32x4 v = *(const u32x4*)(p0 + (size_t)p * 400 * 32768 + jj * 256 + g * 16);
            #pragma unroll
            for (int e = 0; e < 4; ++e) {
                sum[2 * e + 0] += bitsf(v[e] << 16);
                sum[2 * e + 1] += bitsf(v[e] & 0xFFFF0000u);
            }
        }
        float* q = sMT + jj * 132 + g * 8;
        #pragma unroll
        for (int e = 0; e < 8; ++e) q[e] = sum[e];
    }
    __syncthreads();
    char* outN = Mbf + (size_t)s * 65536;
    char* outT = outN + 32768;
    #pragma unroll
    for (int it = 0; it < 16; ++it) {
        const int item = it * 256 + tid;       // 4096 = 2 lay x (128 r x 16 grp)
        const int lay = item >> 11;
        const int g2 = item & 2047;
        const int rr = g2 >> 4, grp = g2 & 15;
        const int g = grp ^ (rr & 7);
        u32x4 o;
        if (lay == 0) {                        // t-layout: M^T row rr contiguous
            const float* p = sMT + rr * 132 + g * 8;
            const v4f a = *(const v4f*)p, bq = *(const v4f*)(p + 4);
            o[0] = pk2(a[0], a[1]);   o[1] = pk2(a[2], a[3]);
            o[2] = pk2(bq[0], bq[1]); o[3] = pk2(bq[2], bq[3]);
            *(u32x4*)(outT + rr * 256 + grp * 16) = o;
        } else {                               // n-layout: M row rr = sMT column
            const float* p = sMT + (g * 8) * 132 + rr;
            o[0] = pk2(p[0],   p[132]); o[1] = pk2(p[264], p[396]);
            o[2] = pk2(p[528], p[660]); o[3] = pk2(p[792], p[924]);
            *(u32x4*)(outN + rr * 256 + grp * 16) = o;
        }
    }
}

// ============================= stage 2 ======================================
// blocks [0,200): l_pre residual GEMMs via MFMA from pre-built bf16 tiles.
// blocks [200,232): small losses (bij/orth/lap), verified fp32 path.
extern "C" __global__ __launch_bounds__(256, 1)
void surfm_stage2(const float* __restrict__ C12g, const float* __restrict__ C21g,
                  const float* __restrict__ ev1g, const float* __restrict__ ev2g,
                  const char* __restrict__ Cbf, const char* __restrict__ Mbf,
                  float* __restrict__ out, int N, int ND)
{
    extern __shared__ char sm[];
    const int b = blockIdx.x;
    const int tid = threadIdx.x;
    const int nPre = N * ND;

    if (b < nPre) {
        const int n = b & 7, d = b >> 3;
        const size_t slot = n * 25 + d;
        const int l = tid & 63;
        const int wq = __builtin_amdgcn_readfirstlane(tid >> 6);
        const int lm = l & 15, lk = (l >> 4) * 8;
        const int wm = wq >> 1, wj = wq & 1;
        float rsum = 0.0f;

        #pragma unroll 1
        for (int ph = 0; ph < 2; ++ph) {
            const char* s0 = Cbf + ((size_t)(ph * 8 + n) * 2 + 0) * CTILE_B;
            const char* s1 = Mbf + (slot * 2 + (ph ? 1 : 0)) * 65536 + 32768;
            const char* s2 = Mbf + (slot * 2 + (ph ? 0 : 1)) * 65536;
            const char* s3 = Cbf + ((size_t)(ph * 8 + n) * 2 + 1) * CTILE_B;
            const char* gs = (wq == 0) ? s0 : (wq == 1) ? s1 : (wq == 2) ? s2 : s3;
            char* ld = sm + wq * 32768;
            if (ph) __builtin_amdgcn_s_barrier();
            #pragma unroll
            for (int i = 0; i < 32; ++i)
                gload_lds16(gs + i * 1024 + l * 16, ld + i * 1024);
            asm volatile("s_waitcnt vmcnt(0)" ::: "memory");
            __builtin_amdgcn_s_barrier();
            __builtin_amdgcn_sched_barrier(0);

            v4f as_[4][4], at_[4][4];
            #pragma unroll
            for (int mf = 0; mf < 4; ++mf)
                #pragma unroll
                for (int jf = 0; jf < 4; ++jf) {
                    as_[mf][jf] = (v4f){0.f,0.f,0.f,0.f};
                    at_[mf][jf] = (v4f){0.f,0.f,0.f,0.f};
                }
            #pragma unroll
            for (int ks = 0; ks < 4; ++ks) {
                const int kb = ks * 64 + lk * 2;
                B8 bS[4], bT[4];
                #pragma unroll
                for (int jf = 0; jf < 4; ++jf) {
                    const int jj = wj * 64 + jf * 16 + lm;
                    const int off = jj * 256 + (kb ^ ((jj & 7) << 4));
                    bS[jf].u = *(const u32x4*)(sm + 32768 + off);
                    bT[jf].u = *(const u32x4*)(sm + 98304 + off);
                }
                #pragma unroll
                for (int mf = 0; mf < 4; ++mf) {
                    const int r = wm * 64 + mf * 16 + lm;
                    const int off = r * 256 + (kb ^ ((r & 7) << 4));
                    B8 aS; aS.u = *(const u32x4*)(sm + off);
                    B8 aT; aT.u = *(const u32x4*)(sm + 65536 + off);
                    #pragma unroll
                    for (int jf = 0; jf < 4; ++jf) {
                        as_[mf][jf] = __builtin_amdgcn_mfma_f32_16x16x32_bf16(aS.h, bS[jf].h, as_[mf][jf], 0, 0, 0);
                        at_[mf][jf] = __builtin_amdgcn_mfma_f32_16x16x32_bf16(aT.h, bT[jf].h, at_[mf][jf], 0, 0, 0);
                    }
                }
            }
            #pragma unroll
            for (int mf = 0; mf < 4; ++mf)
                #pragma unroll
                for (int jf = 0; jf < 4; ++jf) {
                    const v4f df = as_[mf][jf] - at_[mf][jf];
                    rsum += df[0]*df[0] + df[1]*df[1] + df[2]*df[2] + df[3]*df[3];
                }
        }
        #pragma unroll
        for (int off = 32; off; off >>= 1) rsum += __shfl_down(rsum, off, 64);
        if (l == 0)
            atomicAdd(out + 3, rsum * (W_PRE / (float)(N * K * K)));
    } else {
        // --------------------------- small losses ---------------------------
        float* lds = (float*)sm;
        const int idx = b - nPre;
        const int n = idx >> 2, p = idx & 3;
        const float* c12 = C12g + (size_t)n * K * K;
        const float* c21 = C21g + (size_t)n * K * K;
        const float* Xg = (p == 1 || p == 3) ? c21 : c12;
        const float* Yg = (p == 0) ? c21 : c12;
        const float* ea = (p == 0) ? ev1g + n * K : ev2g + n * K;
        const float* eb = (p == 0) ? ev2g + n * K : ev1g + n * K;
        float* X = lds;             // [K][129]
        float* Y = lds + K * 129;
        const int tx = tid & 15, ty = tid >> 4;
        float lap = 0.0f;
        for (int i = tid; i < K * K / 4; i += 256) {
            const int r = i >> 5, c4 = (i & 31) * 4;
            const v4f x = *(const v4f*)(Xg + r * K + c4);
            X[r * 129 + c4 + 0] = x[0]; X[r * 129 + c4 + 1] = x[1];
            X[r * 129 + c4 + 2] = x[2]; X[r * 129 + c4 + 3] = x[3];
            if (p < 2) {
                const v4f y = *(const v4f*)(Yg + r * K + c4);
                Y[r * 129 + c4 + 0] = y[0]; Y[r * 129 + c4 + 1] = y[1];
                Y[r * 129 + c4 + 2] = y[2]; Y[r * 129 + c4 + 3] = y[3];
                const float ebi = eb[r];
                #pragma unroll
                for (int e = 0; e < 4; ++e) {
                    const float dlt = ea[c4 + e] - ebi;
                    lap += x[e] * x[e] * dlt * dlt;
                }
            }
        }
        __syncthreads();
        const int i0 = ty * 8, k0 = tx * 8;
        float z[8][8];
        #pragma unroll
        for (int i = 0; i < 8; ++i)
            #pragma unroll
            for (int t = 0; t < 8; ++t) z[i][t] = 0.0f;
        for (int jj = 0; jj < K; ++jj) {
            float xi[8], yk[8];
            if (p < 2) {
                #pragma unroll
                for (int i = 0; i < 8; ++i) xi[i] = X[(i0 + i) * 129 + jj];
                #pragma unroll
                for (int t = 0; t < 8; ++t) yk[t] = Y[jj * 129 + k0 + t];
            } else {
                #pragma unroll
                for (int i = 0; i < 8; ++i) xi[i] = X[jj * 129 + i0 + i];
                #pragma unroll
                for (int t = 0; t < 8; ++t) yk[t] = X[jj * 129 + k0 + t];
            }
            #pragma unroll
            for (int i = 0; i < 8; ++i)
                #pragma unroll
                for (int t = 0; t < 8; ++t) z[i][t] += xi[i] * yk[t];
        }
        float sacc = 0.0f;
        #pragma unroll
        for (int i = 0; i < 8; ++i)
            #pragma unroll
            for (int t = 0; t < 8; ++t) {
                const float e = z[i][t] - ((i0 + i) == (k0 + t) ? 1.0f : 0.0f);
                sacc += e * e;
            }
        #pragma unroll
        for (int off = 32; off; off >>= 1) {
            sacc += __shfl_down(sacc, off, 64);
            lap  += __shfl_down(lap, off, 64);
        }
        if ((tid & 63) == 0) {
            if (p < 2) {
                atomicAdd(out + 0, sacc * (W_BIJ / (float)N));
                atomicAdd(out + 2, lap * (W_LAP / (float)N));
            } else {
                atomicAdd(out + 1, sacc * (W_ORTH / (float)N));
            }
        }
    }
}

// ================= fallback: round-2 verified fused kernel =================
extern "C" __global__ __launch_bounds__(256, 1)
void surfm_fused(const float* __restrict__ C12g, const float* __restrict__ C21g,
                 const float* __restrict__ F1, const float* __restrict__ F2,
                 const float* __restrict__ E1g, const float* __restrict__ E2g,
                 const float* __restrict__ T1, const float* __restrict__ T2,
                 const float* __restrict__ ev1g, const float* __restrict__ ev2g,
                 const int* __restrict__ desc, float* __restrict__ out,
                 int N, int ND, int V, int CF)
{
    extern __shared__ char smem[];
    const int b   = blockIdx.x;
    const int tid = threadIdx.x;
    const int nPre = N * ND;

    if (b < nPre) {
        const int n = b & 7;
        const int d = b >> 3;
        const int col = desc[d];
        const float* A1g = T1 + (size_t)n * K * V;
        const float* A2g = T2 + (size_t)n * K * V;
        const float* B1g = E1g + (size_t)n * V * K;
        const float* B2g = E2g + (size_t)n * V * K;
        const float* w1g = F1 + (size_t)n * V * CF;
        const float* w2g = F2 + (size_t)n * V * CF;

        char* As1 = smem;
        char* As2 = smem + 32768;
        char* Bt1 = smem + 65536;
        char* Bt2 = smem + 98304;

        const int l  = tid & 63;
        const int w  = tid >> 6;
        const int lm = l & 15;
        const int lk = (l >> 4) * 8;

        v4f acc1[8][2], acc2[8][2];
        #pragma unroll
        for (int mf = 0; mf < 8; ++mf)
            #pragma unroll
            for (int jf = 0; jf < 2; ++jf) {
                acc1[mf][jf] = (v4f){0.f,0.f,0.f,0.f};
                acc2[mf][jf] = (v4f){0.f,0.f,0.f,0.f};
            }

        for (int v0 = 0; v0 < V; v0 += 128) {
            __syncthreads();
            #pragma unroll 4
            for (int it = 0; it < 16; ++it) {
                const int i  = it * 256 + tid;
                const int r  = i >> 5;
                const int c4 = (i & 31) * 4;
                const int vg = v0 + c4;
                v4f a1 = {0.f,0.f,0.f,0.f}, a2 = {0.f,0.f,0.f,0.f};
                if (vg < V) {
                    a1 = *(const v4f*)(A1g + (size_t)r * V + vg);
                    a2 = *(const v4f*)(A2g + (size_t)r * V + vg);
                }
                const int byte = (r * 256 + c4 * 2) ^ ((r & 7) << 4);
                short4 p1, p2;
                p1.x = (short)f2b(a1[0]); p1.y = (short)f2b(a1[1]);
                p1.z = (short)f2b(a1[2]); p1.w = (short)f2b(a1[3]);
                p2.x = (short)f2b(a2[0]); p2.y = (short)f2b(a2[1]);
                p2.z = (short)f2b(a2[2]); p2.w = (short)f2b(a2[3]);
                *(short4*)(As1 + byte) = p1;
                *(short4*)(As2 + byte) = p2;
            }
            #pragma unroll 2
            for (int it = 0; it < 8; ++it) {
                const int i  = it * 256 + tid;
                const int j4 = (i & 31) * 4;
                const int vp = (i >> 5) * 2;
                const int va = v0 + vp, vb = va + 1;
                v4f e1a = {0.f,0.f,0.f,0.f}, e1b = e1a, e2a = e1a, e2b = e1a;
                if (va < V) {
                    const float w1 = w1g[(size_t)va * CF + col];
                    const float w2 = w2g[(size_t)va * CF + col];
                    e1a = *(const v4f*)(B1g + (size_t)va * K + j4) * w1;
                    e2a = *(const v4f*)(B2g + (size_t)va * K + j4) * w2;
                }
                if (vb < V) {
                    const float w1 = w1g[(size_t)vb * CF + col];
                    const float w2 = w2g[(size_t)vb * CF + col];
                    e1b = *(const v4f*)(B1g + (size_t)vb * K + j4) * w1;
                    e2b = *(const v4f*)(B2g + (size_t)vb * K + j4) * w2;
                }
                #pragma unroll
                for (int e = 0; e < 4; ++e) {
                    const int j = j4 + e;
                    const int key = (((j & 7) ^ ((j >> 3) & 7)) << 4);
                    const int byte = (j * 256 + vp * 2) ^ key;
                    *(u32*)(Bt1 + byte) = pk2(e1a[e], e1b[e]);
                    *(u32*)(Bt2 + byte) = pk2(e2a[e], e2b[e]);
                }
            }
            __syncthreads();
            #pragma unroll
            for (int ks = 0; ks < 4; ++ks) {
                const int k0 = ks * 32 + lk;
                bhalf8 bB1[2], bB2[2];
                #pragma unroll
                for (int jf = 0; jf < 2; ++jf) {
                    const int j = w * 32 + jf * 16 + lm;
                    const int key = (((j & 7) ^ ((j >> 3) & 7)) << 4);
                    const int byte = (j * 256 + k0 * 2) ^ key;
                    bB1[jf] = *(const bhalf8*)(Bt1 + byte);
                    bB2[jf] = *(const bhalf8*)(Bt2 + byte);
                }
                #pragma unroll
                for (int mf = 0; mf < 8; ++mf) {
                    const int r = mf * 16 + lm;
                    const int byte = (r * 256 + k0 * 2) ^ ((r & 7) << 4);
                    const bhalf8 a1 = *(const bhalf8*)(As1 + byte);
                    const bhalf8 a2 = *(const bhalf8*)(As2 + byte);
                    acc1[mf][0] = __builtin_amdgcn_mfma_f32_16x16x32_bf16(a1, bB1[0], acc1[mf][0], 0, 0, 0);
                    acc1[mf][1] = __builtin_amdgcn_mfma_f32_16x16x32_bf16(a1, bB1[1], acc1[mf][1], 0, 0, 0);
                    acc2[mf][0] = __builtin_amdgcn_mfma_f32_16x16x32_bf16(a2, bB2[0], acc2[mf][0], 0, 0, 0);
                    acc2[mf][1] = __builtin_amdgcn_mfma_f32_16x16x32_bf16(a2, bB2[1], acc2[mf][1], 0, 0, 0);
                }
            }
        }
        __syncthreads();
        float* M1 = (float*)smem;
        float* M2 = (float*)smem + K * K;
        #pragma unroll
        for (int mf = 0; mf < 8; ++mf)
            #pragma unroll
            for (int jf = 0; jf < 2; ++jf)
                #pragma unroll
                for (int rg = 0; rg < 4; ++rg) {
                    const int row = mf * 16 + ((l >> 4) << 2) + rg;
                    const int cj  = w * 32 + jf * 16 + lm;
                    const int pc  = ((((cj >> 2) ^ ((row >> 3) & 7)) << 2) | (cj & 3));
                    M1[row * K + pc] = acc1[mf][jf][rg];
                    M2[row * K + pc] = acc2[mf][jf][rg];
                }
        __syncthreads();

        const int tx = tid & 15, ty = tid >> 4;
        const int r0 = ty * 8;
        const int ca = tx * 4, cb = 64 + tx * 4;
        const int kcol = ty & 7;
        const float* c12 = C12g + (size_t)n * K * K;
        const float* c21 = C21g + (size_t)n * K * K;
        v4f acc1a[8], acc1b[8], acc2a[8], acc2b[8];
        #pragma unroll
        for (int i = 0; i < 8; ++i) {
            acc1a[i] = (v4f){0,0,0,0}; acc1b[i] = (v4f){0,0,0,0};
            acc2a[i] = (v4f){0,0,0,0}; acc2b[i] = (v4f){0,0,0,0};
        }
        for (int jj = 0; jj < K; ++jj) {
            const int keyj = (jj >> 3) & 7;
            const int ga = (tx ^ keyj) << 2;
            const int gb = ((16 + tx) ^ keyj) << 2;
            const v4f m1ra = *(const v4f*)(M1 + jj * K + ga);
            const v4f m1rb = *(const v4f*)(M1 + jj * K + gb);
            const v4f m2ra = *(const v4f*)(M2 + jj * K + ga);
            const v4f m2rb = *(const v4f*)(M2 + jj * K + gb);
            const v4f c12ra = *(const v4f*)(c12 + jj * K + ca);
            const v4f c12rb = *(const v4f*)(c12 + jj * K + cb);
            const v4f c21ra = *(const v4f*)(c21 + jj * K + ca);
            const v4f c21rb = *(const v4f*)(c21 + jj * K + cb);
            const int jp = (((jj >> 2) ^ kcol) << 2) | (jj & 3);
            #pragma unroll
            for (int i = 0; i < 8; ++i) {
                const int r = r0 + i;
                const float x12 = c12[r * K + jj];
                const float x21 = c21[r * K + jj];
                const float m1c = M1[r * K + jp];
                const float m2c = M2[r * K + jp];
                acc1a[i] += m1ra * x12; acc1a[i] -= c12ra * m2c;
                acc1b[i] += m1rb * x12; acc1b[i] -= c12rb * m2c;
                acc2a[i] += m2ra * x21; acc2a[i] -= c21ra * m1c;
                acc2b[i] += m2rb * x21; acc2b[i] -= c21rb * m1c;
            }
        }
        float s = 0.0f;
        #pragma unroll
        for (int i = 0; i < 8; ++i)
            #pragma unroll
            for (int e = 0; e < 4; ++e) {
                s += acc1a[i][e] * acc1a[i][e] + acc1b[i][e] * acc1b[i][e];
                s += acc2a[i][e] * acc2a[i][e] + acc2b[i][e] * acc2b[i][e];
            }
        #pragma unroll
        for (int off = 32; off; off >>= 1) s += __shfl_down(s, off, 64);
        if ((tid & 63) == 0)
            atomicAdd(out + 3, s * (W_PRE / (float)(N * K * K)));
    } else {
        float* ldsf = (float*)smem;
        const int idx = b - nPre;
        const int n = idx >> 2, p = idx & 3;
        const float* c12 = C12g + (size_t)n * K * K;
        const float* c21 = C21g + (size_t)n * K * K;
        const float* Xg = (p == 1 || p == 3) ? c21 : c12;
        const float* Yg = (p == 0) ? c21 : c12;
        const float* ea = (p == 0) ? ev1g + n * K : ev2g + n * K;
        const float* eb = (p == 0) ? ev2g + n * K : ev1g + n * K;
        float* X = ldsf;
        float* Y = ldsf + K * 129;
        const int tx = tid & 15, ty = tid >> 4;
        float lap = 0.0f;
        for (int i = tid; i < K * K / 4; i += 256) {
            const int r = i >> 5, c4 = (i & 31) * 4;
            const v4f x = *(const v4f*)(Xg + r * K + c4);
            X[r * 129 + c4 + 0] = x[0]; X[r * 129 + c4 + 1] = x[1];
            X[r * 129 + c4 + 2] = x[2]; X[r * 129 + c4 + 3] = x[3];
            if (p < 2) {
                const v4f y = *(const v4f*)(Yg + r * K + c4);
                Y[r * 129 + c4 + 0] = y[0]; Y[r * 129 + c4 + 1] = y[1];
                Y[r * 129 + c4 + 2] = y[2]; Y[r * 129 + c4 + 3] = y[3];
                const float ebi = eb[r];
                #pragma unroll
                for (int e = 0; e < 4; ++e) {
                    const float dlt = ea[c4 + e] - ebi;
                    lap += x[e] * x[e] * dlt * dlt;
                }
            }
        }
        __syncthreads();
        const int i0 = ty * 8, k0 = tx * 8;
        float z[8][8];
        #pragma unroll
        for (int i = 0; i < 8; ++i)
            #pragma unroll
            for (int t = 0; t < 8; ++t) z[i][t] = 0.0f;
        for (int jj = 0; jj < K; ++jj) {
            float xi[8], yk[8];
            if (p < 2) {
                #pragma unroll
                for (int i = 0; i < 8; ++i) xi[i] = X[(i0 + i) * 129 + jj];
                #pragma unroll
                for (int t = 0; t < 8; ++t) yk[t] = Y[jj * 129 + k0 + t];
            } else {
                #pragma unroll
                for (int i = 0; i < 8; ++i) xi[i] = X[jj * 129 + i0 + i];
                #pragma unroll
                for (int t = 0; t < 8; ++t) yk[t] = X[jj * 129 + k0 + t];
            }
            #pragma unroll
            for (int i = 0; i < 8; ++i)
                #pragma unroll
                for (int t = 0; t < 8; ++t) z[i][t] += xi[i] * yk[t];
        }
        float s = 0.0f;
        #pragma unroll
        for (int i = 0; i < 8; ++i)
            #pragma unroll
            for (int t = 0; t < 8; ++t) {
                const float e = z[i][t] - ((i0 + i) == (k0 + t) ? 1.0f : 0.0f);
                s += e * e;
            }
        #pragma unroll
        for (int off = 32; off; off >>= 1) {
            s   += __shfl_down(s, off, 64);
            lap += __shfl_down(lap, off, 64);
        }
        if ((tid & 63) == 0) {
            if (p < 2) {
                atomicAdd(out + 0, s * (W_BIJ / (float)N));
                atomicAdd(out + 2, lap * (W_LAP / (float)N));
            } else {
                atomicAdd(out + 1, s * (W_ORTH / (float)N));
            }
        }
    }
}

extern "C" void kernel_launch(void* const* d_in, const int* in_sizes, int n_in,
                              void* d_out, int out_size, void* d_ws, size_t ws_size,
                              hipStream_t stream) {
    (void)n_in;
    const float* C12 = (const float*)d_in[0];
    const float* C21 = (const float*)d_in[1];
    const float* F1  = (const float*)d_in[2];
    const float* F2  = (const float*)d_in[3];
    const float* E1  = (const float*)d_in[4];
    const float* E2  = (const float*)d_in[5];
    const float* T1  = (const float*)d_in[6];
    const float* T2  = (const float*)d_in[7];
    const float* ev1 = (const float*)d_in[8];
    const float* ev2 = (const float*)d_in[9];
    const int* desc  = (const int*)d_in[10];
    float* out = (float*)d_out;

    const int N  = in_sizes[8] / K;            // evals_1: N*K
    const int ND = in_sizes[10];               // desc_ind
    const int V  = in_sizes[4] / (N * K);      // evecs_1: N*V*K
    const int CF = in_sizes[2] / (N * V);      // feat_1: N*V*C

    hipMemsetAsync(d_out, 0, (size_t)out_size * sizeof(float), stream);

    const size_t ABF = (size_t)16 * NCH * TILE_B;        // 20,709,376
    const size_t EBF = ABF;                              // 20,709,376
    const size_t FBF = (size_t)400 * WSLOT_B;            //  4,096,000
    const size_t CBF = (size_t)32 * CTILE_B;             //  1,048,576
    const size_t MBF = (size_t)400 * 65536;              // 26,214,400
    const size_t MPB = (size_t)2 * 400 * 32768;          // 26,214,400
    const size_t base = ABF + EBF + FBF + CBF + MBF;
    const size_t needPart = base + MPB;                  // 98,992,128

    const bool okShape = (N == 8 && ND == 25 && V == 5000 && CF == 128);
    if (!okShape || ws_size < needPart) {
        const size_t shmem = (size_t)(2 * K * 129) * sizeof(float);  // 132096
        hipFuncSetAttribute((const void*)surfm_fused,
                            hipFuncAttributeMaxDynamicSharedMemorySize, (int)shmem);
        const int blocks = N * ND + 4 * N;
        surfm_fused<<<blocks, 256, shmem, stream>>>(C12, C21, F1, F2, E1, E2, T1, T2,
                                                    ev1, ev2, desc, out, N, ND, V, CF);
        return;
    }

    char* ws = (char*)d_ws;
    unsigned short* Abf = (unsigned short*)ws;
    unsigned short* Ebf = (unsigned short*)(ws + ABF);
    char* Fbf = ws + ABF + EBF;
    char* Cbf = ws + ABF + EBF + FBF;
    char* Mbf = ws + ABF + EBF + FBF + CBF;
    char* MpartB = ws + base;

    surfm_conv<<<2944, 256, 0, stream>>>(T1, T2, E1, E2, F1, F2, C12, C21, desc,
                                         Abf, Ebf, Fbf, Cbf, V, CF);

    const size_t shmem1 = 43008;    // A dbuf 32K + w 10K
    hipFuncSetAttribute((const void*)surfm_stage1,
                        hipFuncAttributeMaxDynamicSharedMemorySize, (int)shmem1);
    surfm_stage1<<<416, 512, shmem1, stream>>>((const char*)Abf, (const char*)Ebf,
                                               Fbf, MpartB);

    const size_t shmemM = (size_t)128 * 132 * 4;   // 67584
    hipFuncSetAttribute((const void*)surfm_mconv,
                        hipFuncAttributeMaxDynamicSharedMemorySize, (int)shmemM);
    surfm_mconv<<<400, 256, shmemM, stream>>>(MpartB, Mbf);

    const size_t shmem2 = 132096;
    hipFuncSetAttribute((const void*)surfm_stage2,
                        hipFuncAttributeMaxDynamicSharedMemorySize, (int)shmem2);
    surfm_stage2<<<N * ND + 4 * N, 256, shmem2, stream>>>(C12, C21, ev1, ev2,
                                                          Cbf, Mbf, out, N, ND);
}